// Round 1
// baseline (58.301 us; speedup 1.0000x reference)
//
#include <hip/hip_runtime.h>
#include <math.h>

// out[b,l,f] = x * (1/(sigma*sqrt(2pi))) * sum_j exp(-(j-f)^2/(2 sigma^2))
// Truncated at |j-f| <= 32: with sigma <= 2.5, the d=33 term is exp(-87) ~ 1e-38.
// Symmetric-d trick: each exp computed once, weighted by # of valid sides (0/1/2).

#define FDIM 1024
#define DMAX 32

__global__ __launch_bounds__(256) void gaussian_kernel(
    const float* __restrict__ x,
    const float* __restrict__ sigma,
    float* __restrict__ out,
    int n)
{
    int idx = blockIdx.x * blockDim.x + threadIdx.x;
    if (idx >= n) return;

    int f = idx & (FDIM - 1);
    float sg = sigma[idx];
    float xv = x[idx];

    float a = 1.0f / (2.0f * sg * sg);
    // exp(-a*d^2) = exp2(c*d^2), c = -a*log2(e)
    float c = -a * 1.4426950408889634f;

    float s = 1.0f;  // d = 0 term
    #pragma unroll
    for (int d = 1; d <= DMAX; ++d) {
        float e = exp2f(c * (float)(d * d));
        // count valid sides: j = f-d >= 0 and j = f+d <= FDIM-1
        float cnt = (f >= d ? 1.0f : 0.0f) + (f + d <= FDIM - 1 ? 1.0f : 0.0f);
        s = fmaf(e, cnt, s);
    }

    const float INV_SQRT_2PI = 0.3989422804014327f;
    out[idx] = xv * (INV_SQRT_2PI / sg) * s;
}

extern "C" void kernel_launch(void* const* d_in, const int* in_sizes, int n_in,
                              void* d_out, int out_size, void* d_ws, size_t ws_size,
                              hipStream_t stream) {
    const float* x     = (const float*)d_in[0];
    const float* sigma = (const float*)d_in[1];
    float* out = (float*)d_out;
    int n = out_size;  // B*L*F = 8*32*1024 = 262144

    int block = 256;
    int grid = (n + block - 1) / block;
    gaussian_kernel<<<grid, block, 0, stream>>>(x, sigma, out, n);
}

// Round 2
// 57.170 us; speedup vs baseline: 1.0198x; 1.0198x over previous
//
#include <hip/hip_runtime.h>
#include <math.h>

// out[b,l,f] = x * (1/(sigma*sqrt(2pi))) * sum_j exp(-(j-f)^2/(2 sigma^2))
// Truncated at |j-f| <= 16: with sigma <= 2.5 the d=16 term is exp(-20.5) ~ 1.2e-9,
// tail sum ~1e-8 in the output vs a 9.9e-2 absmax threshold.
// Symmetric-d trick: each exp computed once, weighted by # of valid sides (0/1/2).
// float4-vectorized: 4 elements/thread, 16 B/lane loads/stores, 4 independent
// exp chains per lane for ILP over the v_exp_f32 latency.

#define FDIM 1024
#define DMAX 16

__global__ __launch_bounds__(256) void gaussian_kernel(
    const float4* __restrict__ x4,
    const float4* __restrict__ sg4,
    float4* __restrict__ out4,
    int n4)
{
    int idx = blockIdx.x * blockDim.x + threadIdx.x;
    if (idx >= n4) return;

    float4 xv = x4[idx];
    float4 sg = sg4[idx];
    int f0 = (idx * 4) & (FDIM - 1);   // F=1024 divisible by 4: all 4 elems share row

    float xs[4] = {xv.x, xv.y, xv.z, xv.w};
    float ss[4] = {sg.x, sg.y, sg.z, sg.w};
    float rs[4];

    #pragma unroll
    for (int k = 0; k < 4; ++k) {
        float s = ss[k];
        int f = f0 + k;
        // exp(-d^2/(2 s^2)) = exp2(c * d^2), c = -log2(e)/(2 s^2)
        float c = -0.7213475204444817f / (s * s);
        float acc = 1.0f;   // d = 0 term
        #pragma unroll
        for (int d = 1; d <= DMAX; ++d) {
            float e = exp2f(c * (float)(d * d));
            float cnt = (f >= d ? 1.0f : 0.0f) + (f + d <= FDIM - 1 ? 1.0f : 0.0f);
            acc = fmaf(e, cnt, acc);
        }
        const float INV_SQRT_2PI = 0.3989422804014327f;
        rs[k] = xs[k] * (INV_SQRT_2PI / s) * acc;
    }

    float4 r = make_float4(rs[0], rs[1], rs[2], rs[3]);
    out4[idx] = r;
}

extern "C" void kernel_launch(void* const* d_in, const int* in_sizes, int n_in,
                              void* d_out, int out_size, void* d_ws, size_t ws_size,
                              hipStream_t stream) {
    const float4* x4  = (const float4*)d_in[0];
    const float4* sg4 = (const float4*)d_in[1];
    float4* out4 = (float4*)d_out;
    int n4 = out_size / 4;   // 262144 / 4 = 65536

    int block = 256;
    int grid = (n4 + block - 1) / block;   // 256 blocks
    gaussian_kernel<<<grid, block, 0, stream>>>(x4, sg4, out4, n4);
}